// Round 4
// baseline (138.567 us; speedup 1.0000x reference)
//
#include <hip/hip_runtime.h>
#include <math.h>

// Fused DETR HungarianMatcher cost matrix, MI355X.
// Shapes: pred_logits [14400,151] f32, pred_boxes [14400,4] f32,
//         tgt_labels [1600] i32, tgt_boxes [1600,4] f32
//         out C [14400,1600] f32
// One kernel: each block owns 32 rows x 320 targets. Stages the 32x151 logit
// slice into LDS (float4, contiguous), converts it to softmax probs in place
// (wave-per-row shuffle reduction), then the 32-row inner loop does an LDS
// prob gather + box costs with fully coalesced dword stores along t.
// No workspace usage at all (harness poisons ws every iter; don't touch it).
#define NROWS 14400
#define NT    1600
#define NC    151
#define RPB   32
#define TPB   320                 // 5 waves
#define QUADS ((RPB * NC) / 4)    // 1208 float4s = 19328 B

__global__ __launch_bounds__(TPB) void matcher_fused(
    const float* __restrict__ logits,
    const float* __restrict__ pboxes,
    const int*   __restrict__ tlabels,
    const float* __restrict__ tboxes,
    float* __restrict__ out)
{
    __shared__ __align__(16) float sprob[RPB * NC];   // logits -> probs, 19328 B
    __shared__ __align__(16) float srow[RPB * 12];    // per-row box descriptor

    const int tid  = threadIdx.x;
    const int r0   = blockIdx.y * RPB;
    const int wave = tid >> 6;
    const int lane = tid & 63;

    // --- phase 1a: stage 32 rows of logits (contiguous 4832 floats) ---
    {
        const float4* g4 = (const float4*)(logits + (size_t)r0 * NC); // 16B-aligned: r0*151*4 = by*19328
        float4* s4 = (float4*)sprob;
        for (int i = tid; i < QUADS; i += TPB) s4[i] = g4[i];
    }
    // --- phase 1b: row box descriptors ---
    if (tid < RPB) {
        float4 pb = ((const float4*)pboxes)[r0 + tid];
        float x0 = pb.x - 0.5f * pb.z, y0 = pb.y - 0.5f * pb.w;
        float x1 = pb.x + 0.5f * pb.z, y1 = pb.y + 0.5f * pb.w;
        float* o = srow + tid * 12;
        ((float4*)o)[0] = pb;
        ((float4*)o)[1] = make_float4(x0, y0, x1, y1);
        o[8] = (x1 - x0) * (y1 - y0);
    }
    // --- phase 1c: per-thread target registers ---
    const int t = blockIdx.x * TPB + tid;             // < 1600 always (grid.x=5)
    const float4 tb = ((const float4*)tboxes)[t];
    const int label = tlabels[t];
    const float tx0 = tb.x - 0.5f * tb.z, ty0 = tb.y - 0.5f * tb.w;
    const float tx1 = tb.x + 0.5f * tb.z, ty1 = tb.y + 0.5f * tb.w;
    const float tarea = (tx1 - tx0) * (ty1 - ty0);

    __syncthreads();

    // --- phase 2: in-place softmax per row; wave w handles rows w, w+5, ...
    for (int i = wave; i < RPB; i += TPB / 64) {
        float* row = sprob + i * NC;
        float v0 = row[lane];
        float v1 = row[lane + 64];
        float v2 = (lane < NC - 128) ? row[lane + 128] : -3.4e38f;
        float m = fmaxf(fmaxf(v0, v1), v2);
        #pragma unroll
        for (int off = 32; off; off >>= 1) m = fmaxf(m, __shfl_xor(m, off, 64));
        float e0 = __expf(v0 - m), e1 = __expf(v1 - m);
        float e2 = (lane < NC - 128) ? __expf(v2 - m) : 0.0f;
        float s = e0 + e1 + e2;
        #pragma unroll
        for (int off = 32; off; off >>= 1) s += __shfl_xor(s, off, 64);
        const float rinv = 1.0f / s;
        row[lane]      = e0 * rinv;
        row[lane + 64] = e1 * rinv;
        if (lane < NC - 128) row[lane + 128] = e2 * rinv;
    }
    __syncthreads();

    // --- phase 3: 32-row inner loop, coalesced dword stores along t ---
    size_t oaddr = (size_t)r0 * NT + t;
    #pragma unroll 4
    for (int i = 0; i < RPB; ++i) {
        const float4 pb  = *(const float4*)(srow + i * 12);      // cx,cy,w,h (broadcast)
        const float4 pxy = *(const float4*)(srow + i * 12 + 4);  // x0,y0,x1,y1
        const float parea = srow[i * 12 + 8];

        const float cls = sprob[i * NC + label];                 // LDS prob gather

        const float l1 = fabsf(pb.x - tb.x) + fabsf(pb.y - tb.y) +
                         fabsf(pb.z - tb.z) + fabsf(pb.w - tb.w);

        const float iw = fmaxf(fminf(pxy.z, tx1) - fmaxf(pxy.x, tx0), 0.0f);
        const float ih = fmaxf(fminf(pxy.w, ty1) - fmaxf(pxy.y, ty0), 0.0f);
        const float inter = iw * ih;
        const float uni   = parea + tarea - inter;
        const float iou   = inter * __builtin_amdgcn_rcpf(uni);
        const float ew = fmaxf(pxy.z, tx1) - fminf(pxy.x, tx0);
        const float eh = fmaxf(pxy.w, ty1) - fminf(pxy.y, ty0);
        const float earea = ew * eh;
        const float giou  = iou - (earea - uni) * __builtin_amdgcn_rcpf(earea);

        out[oaddr] = 5.0f * l1 - cls - 2.0f * giou;
        oaddr += NT;
    }
}

extern "C" void kernel_launch(void* const* d_in, const int* in_sizes, int n_in,
                              void* d_out, int out_size, void* d_ws, size_t ws_size,
                              hipStream_t stream) {
    const float* logits  = (const float*)d_in[0];
    const float* pboxes  = (const float*)d_in[1];
    const int*   tlabels = (const int*)d_in[2];
    const float* tboxes  = (const float*)d_in[3];
    float* out = (float*)d_out;
    (void)d_ws; (void)ws_size; (void)out_size; (void)in_sizes; (void)n_in;

    matcher_fused<<<dim3(NT / TPB, NROWS / RPB), TPB, 0, stream>>>(
        logits, pboxes, tlabels, tboxes, out);
}